// Round 13
// baseline (168.072 us; speedup 1.0000x reference)
//
#include <hip/hip_runtime.h>

// ConvNet_STDP — 3 regular kernels, stream-ordered, NO cooperative launch.
//
// Verified (rounds 1-12, absmax 0.0):
//  * STDP provably inert -> weight outputs are clip(w_init, 0, 1).
//  * Network dies at t=0 for this input; gated per-batch fallback is fully
//    self-contained (recomputes everything from x, exact reference order).
//  * R12 post-mortem: per-DISPATCH overhead ~5-7us (dispatch ramp + inter-
//    kernel L2 coherency across 8 XCDs) dominates: 4 boundaries ~ 24us of
//    46.7. This round: 3 dispatches, and conv2 collapsed via the all-ones
//    shortcut (z3 a.s. all-ones at t=0 -> per-channel full-tap sums S_c,
//    20K adds instead of 157M masked adds; general exact-order path kept
//    for non-all-ones inputs). z5 global buffer + 3840-block kernel deleted.
//  * Decision-rounding risk class unchanged (margins ~819 vs 60, ~400 vs 2;
//    absmax 0.0 across four different summation orders in R6-R12).

#define T_STEPS 30
#define BATCH   32
#define H_IN    240
#define W_IN    160
#define C1      4
#define H1      236
#define W1O     156
#define H3      39
#define W3      25
#define C2      20
#define H2      24
#define W2O     10
#define C3      10
#define H8      8

#define N1PB   (C1*H1*W1O)         // 147,264 per-batch conv1 positions
#define N_V1   (BATCH*N1PB)        // 4,712,448
#define N_V2PB (C2*H2*W2O)         // 4,800
#define Z3PB   (C1*H3*W3)          // 3,900
#define N_Z3   (BATCH*Z3PB)        // 124,800
#define N_POOL (BATCH*H3*W3)       // 31,200
#define N_FEAT (BATCH*C3)          // 320

#define NTHR 256
#define K1_BLOCKS 975              // N_POOL*8 / 256 exactly

// ---- K1: fused conv1+pool1 (t=0, stateless) -> z3; init alive_flag;
//      zero z9; weight-clip outputs ----
__global__ __launch_bounds__(NTHR) void k1_conv1pool(
    const float* __restrict__ x, const float* __restrict__ w1,
    const float* __restrict__ w2,
    unsigned char* __restrict__ z3, int* alive_flag, float* __restrict__ z9,
    float* __restrict__ out_w1, float* __restrict__ out_w2)
{
  __shared__ float s_w1[C1*25];
  for (int i = threadIdx.x; i < C1*25; i += NTHR) s_w1[i] = w1[i];
  __syncthreads();
  int it = blockIdx.x*NTHR + threadIdx.x;
  const int gsz = K1_BLOCKS*NTHR;
  if (it == 0) *alive_flag = 0;
  for (int i = it; i < T_STEPS*N_FEAT; i += gsz) z9[i] = 0.f;   // dead batches stay 0
  for (int i = it; i < C1*25;     i += gsz) out_w1[i] = fminf(fmaxf(w1[i], 0.f), 1.f);
  for (int i = it; i < C2*C1*256; i += gsz) out_w2[i] = fminf(fmaxf(w2[i], 0.f), 1.f);
  int o = it >> 3, q = it & 7;
  int px = o % W3; int tt = o / W3;
  int py = tt % H3; int b = tt / H3;
  unsigned mask = 0;
  if (q < 7) {
    const float* xb = x + (size_t)b*H_IN*W_IN;
    int ybase = py*6 + q;                       // this lane's window row
    float acc[C1][7];
    #pragma unroll
    for (int c = 0; c < C1; ++c)
      #pragma unroll
      for (int wx = 0; wx < 7; ++wx) acc[c][wx] = 0.f;
    #pragma unroll
    for (int i = 0; i < 5; ++i) {
      const float* xp = xb + (size_t)(ybase + i)*W_IN + px*6;
      float xr[11];
      #pragma unroll
      for (int k = 0; k < 11; ++k) xr[k] = xp[k];
      #pragma unroll
      for (int j = 0; j < 5; ++j) {
        float w0 = s_w1[ 0 + i*5 + j];
        float w1v = s_w1[25 + i*5 + j];
        float w2v = s_w1[50 + i*5 + j];
        float w3v = s_w1[75 + i*5 + j];
        #pragma unroll
        for (int wx = 0; wx < 7; ++wx) {
          float xv = xr[wx + j];
          acc[0][wx] = fmaf(xv, w0,  acc[0][wx]);
          acc[1][wx] = fmaf(xv, w1v, acc[1][wx]);
          acc[2][wx] = fmaf(xv, w2v, acc[2][wx]);
          acc[3][wx] = fmaf(xv, w3v, acc[3][wx]);
        }
      }
    }
    #pragma unroll
    for (int c = 0; c < C1; ++c)
      #pragma unroll
      for (int wx = 0; wx < 7; ++wx)
        mask |= (acc[c][wx] >= 10.f) ? (1u << c) : 0u;
  }
  mask |= __shfl_xor(mask, 1, 64);
  mask |= __shfl_xor(mask, 2, 64);
  mask |= __shfl_xor(mask, 4, 64);
  if (q == 0 && o < N_POOL) {
    unsigned char* zp = z3 + (size_t)b*Z3PB + py*W3 + px;
    zp[0]        =  mask       & 1;
    zp[H3*W3]    = (mask >> 1) & 1;
    zp[2*H3*W3]  = (mask >> 2) & 1;
    zp[3*H3*W3]  = (mask >> 3) & 1;
  }
}

// ---- K2B: one block per batch. conv2 decisions (all-ones shortcut or
//      general masked path) -> conv3 (pool folded) -> z9[0][b] when dead;
//      alive -> flag + full exact self-contained fallback (t=0..29). ----
__global__ __launch_bounds__(NTHR) void k2_batch(
    const unsigned char* __restrict__ z3g,
    const float* __restrict__ x,  const float* __restrict__ w1,
    const float* __restrict__ w2, const float* __restrict__ w3,
    float* v1, unsigned char* m1, unsigned char* z2,
    float* __restrict__ z9, int* alive_flag)
{
  const int b = blockIdx.x, tid = threadIdx.x;
  __shared__ float s_w1[C1*25];
  __shared__ unsigned char s_z3[Z3PB];
  __shared__ float s_v2[N_V2PB];
  __shared__ unsigned char s_m2[N_V2PB], s_z5[N_V2PB];
  __shared__ float s_v3[C3*H8];
  __shared__ unsigned char s_m3[C3*H8], s_z8[C3*H8];
  __shared__ float s_part[160], s_S[C2];
  __shared__ int s_allones, s_surv;

  if (tid == 0) { s_allones = 1; s_surv = 0; }
  __syncthreads();
  {
    const unsigned* src = (const unsigned*)(z3g + (size_t)b*Z3PB);
    unsigned* dst = (unsigned*)s_z3;
    int bad = 0;
    for (int i = tid; i < Z3PB/4; i += NTHR) {
      unsigned v = src[i];
      dst[i] = v;
      if (v != 0x01010101u) bad = 1;
    }
    if (bad) s_allones = 0;                     // race-benign (same value)
  }
  __syncthreads();

  int surv = 0;
  if (s_allones) {
    // All window bits set: every output of channel c sums ALL 1024 taps.
    if (tid < 160) {                            // c = tid>>3, 128-tap segment
      const float* wp = w2 + (size_t)(tid >> 3)*1024 + (tid & 7)*128;
      float s = 0.f;
      for (int k = 0; k < 128; ++k) s += wp[k];
      s_part[tid] = s;
    }
    __syncthreads();
    if (tid < C2) {
      float s = 0.f;
      #pragma unroll
      for (int k = 0; k < 8; ++k) s += s_part[tid*8 + k];
      s_S[tid] = s;
    }
    __syncthreads();
    for (int o = tid; o < N_V2PB; o += NTHR) {
      unsigned char sp = (s_S[o / (H2*W2O)] >= 60.0f) ? 1 : 0;
      s_z5[o] = sp;
      surv |= (sp == 0);
    }
  } else {
    // General path: exact-order masked conv2 (rare).
    for (int o = tid; o < N_V2PB; o += NTHR) {
      int c  = o / (H2*W2O);
      int r  = o - c*(H2*W2O);
      int oy = r / W2O, ox = r - (r/W2O)*W2O;
      const float* wb = w2 + (size_t)c*C1*256;
      float s = 0.f;
      for (int ci = 0; ci < C1; ++ci)
        for (int i = 0; i < 16; ++i) {
          const unsigned char* ip = s_z3 + (ci*H3 + oy + i)*W3 + ox;
          const float* wp = wb + ci*256 + i*16;
          #pragma unroll
          for (int j = 0; j < 16; ++j) s = fmaf((float)ip[j], wp[j], s);
        }
      unsigned char sp = (s >= 60.0f) ? 1 : 0;
      s_z5[o] = sp;
      surv |= (sp == 0);
    }
  }
  if (surv) s_surv = 1;                         // race-benign
  __syncthreads();

  if (s_surv == 0) {
    // ---- dead batch (measured case): conv3 (pool2 folded) -> z9[0][b]
    for (int o = tid; o < C3*H8; o += NTHR) {
      int c3 = o >> 3, oy = o & 7;
      float s = 0.f;
      for (int ci = 0; ci < C2; ++ci) {
        const unsigned char* zp = s_z5 + ci*H2*W2O;
        const float* wp = w3 + ((size_t)c3*C2 + ci)*25;
        #pragma unroll
        for (int i = 0; i < 5; ++i) {
          const unsigned char* r0 = zp + (2*(oy + i))*W2O;
          const unsigned char* r1 = r0 + W2O;
          #pragma unroll
          for (int j = 0; j < 5; ++j) {
            unsigned char zv = r0[2*j] | r0[2*j+1] | r1[2*j] | r1[2*j+1];
            s = fmaf((float)zv, wp[i*5 + j], s);
          }
        }
      }
      s_z8[o] = (s >= 2.0f) ? 1 : 0;            // t=0: v=s, m=1
    }
    __syncthreads();
    if (tid < C3) {
      unsigned char r = 0;
      #pragma unroll
      for (int k = 0; k < H8; ++k) r |= s_z8[tid*H8 + k];
      z9[b*C3 + tid] = (float)r;                // z9[0][b][c]; t>=1 stay 0
    }
    return;
  }

  // ---- alive batch: set global flag, run exact self-contained fallback
  if (tid == 0) *alive_flag = 1;
  for (int i = tid; i < C1*25; i += NTHR) s_w1[i] = w1[i];
  float* v1b = v1 + (size_t)b*N1PB;
  unsigned char* m1b = m1 + (size_t)b*N1PB;
  unsigned char* z2b = z2 + (size_t)b*N1PB;
  __syncthreads();

  // t=0: conv1 state (exact order). Fired at t=0 <=> m1b==0.
  const float* x0 = x + (size_t)b*H_IN*W_IN;
  for (int idx = tid; idx < N1PB; idx += NTHR) {
    int xw = idx % W1O; int r = idx / W1O;
    int y  = r % H1;    int c = r / H1;
    const float* xp = x0 + (size_t)y*W_IN + xw;
    const float* wp = s_w1 + c*25;
    float s = 0.f;
    #pragma unroll
    for (int i = 0; i < 5; ++i)
      #pragma unroll
      for (int j = 0; j < 5; ++j) s = fmaf(xp[i*W_IN + j], wp[i*5 + j], s);
    bool z = (s >= 10.0f);
    v1b[idx] = z ? 0.f : s;
    m1b[idx] = z ? 0 : 1;
  }
  __syncthreads();
  // t=0: pool1 from m1b (spike <=> mask cleared at t=0)
  for (int i = tid; i < Z3PB; i += NTHR) {
    int px = i % W3; int r = i / W3;
    int py = r % H3; int cc = r / H3;
    const unsigned char* p = m1b + ((size_t)cc*H1 + py*6)*W1O + px*6;
    unsigned char rr = 0;
    #pragma unroll
    for (int ii = 0; ii < 7; ++ii)
      #pragma unroll
      for (int jj = 0; jj < 7; ++jj) rr |= (p[ii*W1O + jj] == 0) ? 1 : 0;
    s_z3[i] = rr;
  }
  __syncthreads();
  // t=0: conv2 state + exact z5
  for (int o = tid; o < N_V2PB; o += NTHR) {
    int c  = o / (H2*W2O);
    int r  = o - c*(H2*W2O);
    int oy = r / W2O, ox = r - (r/W2O)*W2O;
    const float* wb = w2 + (size_t)c*C1*256;
    float s = 0.f;
    for (int ci = 0; ci < C1; ++ci)
      for (int i = 0; i < 16; ++i) {
        const unsigned char* ip = s_z3 + (ci*H3 + oy + i)*W3 + ox;
        const float* wp = wb + ci*256 + i*16;
        #pragma unroll
        for (int j = 0; j < 16; ++j) s = fmaf((float)ip[j], wp[j], s);
      }
    bool z = (s >= 60.0f);
    s_v2[o] = z ? 0.f : s;
    s_m2[o] = z ? 0 : 1;
    s_z5[o] = z ? 1 : 0;                        // t=0: m=1 -> spike = z
  }
  __syncthreads();
  // t=0: conv3 state + z8 (from exact z5)
  for (int o = tid; o < C3*H8; o += NTHR) {
    int c3 = o >> 3, oy = o & 7;
    float s = 0.f;
    for (int ci = 0; ci < C2; ++ci) {
      const unsigned char* zp = s_z5 + ci*H2*W2O;
      const float* wp = w3 + ((size_t)c3*C2 + ci)*25;
      #pragma unroll
      for (int i = 0; i < 5; ++i) {
        const unsigned char* r0 = zp + (2*(oy + i))*W2O;
        const unsigned char* r1 = r0 + W2O;
        #pragma unroll
        for (int j = 0; j < 5; ++j) {
          unsigned char zv = r0[2*j] | r0[2*j+1] | r1[2*j] | r1[2*j+1];
          s = fmaf((float)zv, wp[i*5 + j], s);
        }
      }
    }
    bool z = (s >= 2.0f);
    s_v3[o] = z ? 0.f : s;
    s_m3[o] = z ? 0 : 1;
    s_z8[o] = z ? 1 : 0;                        // t=0: m=1
  }
  __syncthreads();
  if (tid < C3) {                               // exact z9[0][b]
    unsigned char r = 0;
    #pragma unroll
    for (int k = 0; k < H8; ++k) r |= s_z8[tid*H8 + k];
    z9[b*C3 + tid] = (float)r;
  }
  __syncthreads();

  // exact recurrence t = 1..29 for this batch
  for (int t = 1; t < T_STEPS; ++t) {
    const float* xt = x + ((size_t)t*BATCH + b)*H_IN*W_IN;
    for (int idx = tid; idx < N1PB; idx += NTHR) {        // conv1+IAF
      int xw = idx % W1O; int r = idx / W1O;
      int y  = r % H1;    int c = r / H1;
      const float* xp = xt + (size_t)y*W_IN + xw;
      const float* wp = s_w1 + c*25;
      float s = 0.f;
      #pragma unroll
      for (int i = 0; i < 5; ++i)
        #pragma unroll
        for (int j = 0; j < 5; ++j) s = fmaf(xp[i*W_IN + j], wp[i*5 + j], s);
      float v = v1b[idx] + s;
      bool  z = (v >= 10.0f);
      v1b[idx] = z ? 0.f : v;
      unsigned char m = m1b[idx];
      z2b[idx] = (z && m) ? 1 : 0;
      m1b[idx] = (m && !z) ? 1 : 0;
    }
    __syncthreads();
    for (int i = tid; i < Z3PB; i += NTHR) {              // pool1 = OR
      int px = i % W3; int r = i / W3;
      int py = r % H3; int c = r / H3;
      const unsigned char* p = z2b + ((size_t)c*H1 + py*6)*W1O + px*6;
      unsigned char rr = 0;
      #pragma unroll
      for (int ii = 0; ii < 7; ++ii)
        #pragma unroll
        for (int jj = 0; jj < 7; ++jj) rr |= p[ii*W1O + jj];
      s_z3[i] = rr;
    }
    __syncthreads();
    for (int o = tid; o < N_V2PB; o += NTHR) {            // conv2+IAF
      int c  = o / (H2*W2O);
      int r  = o - c*(H2*W2O);
      int oy = r / W2O, ox = r - (r/W2O)*W2O;
      const float* wb = w2 + (size_t)c*C1*256;
      float s = 0.f;
      for (int ci = 0; ci < C1; ++ci)
        for (int i = 0; i < 16; ++i) {
          const unsigned char* ip = s_z3 + (ci*H3 + oy + i)*W3 + ox;
          const float* wp = wb + ci*256 + i*16;
          #pragma unroll
          for (int j = 0; j < 16; ++j) s = fmaf((float)ip[j], wp[j], s);
        }
      float v = s_v2[o] + s;
      bool  z = (v >= 60.0f);
      s_v2[o] = z ? 0.f : v;
      unsigned char m = s_m2[o];
      s_z5[o] = (z && m) ? 1 : 0;
      s_m2[o] = (m && !z) ? 1 : 0;
    }
    __syncthreads();
    for (int o = tid; o < C3*H8; o += NTHR) {             // conv3+IAF (pool folded)
      int c3 = o >> 3, oy = o & 7;
      float s = 0.f;
      for (int ci = 0; ci < C2; ++ci) {
        const unsigned char* zp = s_z5 + ci*H2*W2O;
        const float* wp = w3 + ((size_t)c3*C2 + ci)*25;
        #pragma unroll
        for (int i = 0; i < 5; ++i) {
          const unsigned char* r0 = zp + (2*(oy + i))*W2O;
          const unsigned char* r1 = r0 + W2O;
          #pragma unroll
          for (int j = 0; j < 5; ++j) {
            unsigned char zv = r0[2*j] | r0[2*j+1] | r1[2*j] | r1[2*j+1];
            s = fmaf((float)zv, wp[i*5 + j], s);
          }
        }
      }
      float v = s_v3[o] + s;
      bool  z = (v >= 2.0f);
      s_v3[o] = z ? 0.f : v;
      unsigned char m = s_m3[o];
      s_z8[o] = (z && m) ? 1 : 0;
      s_m3[o] = (m && !z) ? 1 : 0;
    }
    __syncthreads();
    if (tid < C3) {                                       // z9[t][b][c]
      unsigned char r = 0;
      #pragma unroll
      for (int k = 0; k < H8; ++k) r |= s_z8[tid*H8 + k];
      z9[(size_t)t*N_FEAT + b*C3 + tid] = (float)r;
    }
    __syncthreads();
  }
}

// ---- F2: readout head, single block (closed-form tail when all dead) ----
__global__ __launch_bounds__(NTHR) void f2_head(
    const float* __restrict__ z9,
    const float* __restrict__ fc1_w, const float* __restrict__ fc1_b,
    const float* __restrict__ out_w, const float* __restrict__ out_b,
    float* __restrict__ out, const int* alive_flag)
{
  const int tid = threadIdx.x;
  __shared__ float s_feat[N_FEAT], s_h[64], s_li[10], s_lv[10];
  __shared__ float s_tail[T_STEPS*10];
  if (tid < 10) { s_li[tid] = 0.f; s_lv[tid] = 0.f; }
  __syncthreads();
  const bool alive = (*alive_flag != 0);
  const int tmax = alive ? T_STEPS : 1;

  for (int t = 0; t < tmax; ++t) {
    for (int i = tid; i < N_FEAT; i += NTHR) s_feat[i] = z9[(size_t)t*N_FEAT + i];
    __syncthreads();
    {
      int o = tid >> 2, q = tid & 3;            // 4 lanes per fc1 output
      if (o < 50) {
        const float* wr = fc1_w + (size_t)o*N_FEAT + q*80;
        const float* fr = s_feat + q*80;
        float s = 0.f;
        for (int j = 0; j < 80; ++j) s = fmaf(fr[j], wr[j], s);
        s += __shfl_xor(s, 1, 64);
        s += __shfl_xor(s, 2, 64);
        if (q == 0) s_h[o] = fmaxf(s + fc1_b[o], 0.f);
      }
    }
    __syncthreads();
    if (tid < 10) {
      float idec = s_li[tid]*0.8f;              // 1 - dt*tau_syn_inv
      float vnew = s_lv[tid] + 0.1f*(idec - s_lv[tid]);
      float acc = idec + out_b[tid];
      for (int k = 0; k < 50; ++k) acc = fmaf(s_h[k], out_w[tid*50 + k], acc);
      s_li[tid] = acc;
      s_lv[tid] = vnew;
    }
    __syncthreads();
    float* vt = out + (size_t)t*N_FEAT;
    for (int i = tid; i < N_FEAT; i += NTHR) vt[i] = s_lv[i % 10];
    __syncthreads();
  }

  if (!alive) {                                 // closed-form tail t=1..29
    if (tid < 50) s_h[tid] = fmaxf(fc1_b[tid], 0.f);
    __syncthreads();
    if (tid < 10) {
      float c = out_b[tid];
      for (int k = 0; k < 50; ++k) c = fmaf(s_h[k], out_w[tid*50 + k], c);
      float li = s_li[tid], lv = s_lv[tid];
      for (int tt = 1; tt < T_STEPS; ++tt) {
        float idec = li*0.8f;
        lv = lv + 0.1f*(idec - lv);
        li = idec + c;
        s_tail[(tt - 1)*10 + tid] = lv;
      }
    }
    __syncthreads();
    int nrem = (T_STEPS - 1)*N_FEAT;
    float* vt = out + (size_t)N_FEAT;
    for (int i = tid; i < nrem; i += NTHR)
      vt[i] = s_tail[(i/N_FEAT)*10 + (i % 10)];
  }
}

extern "C" void kernel_launch(void* const* d_in, const int* in_sizes, int n_in,
                              void* d_out, int out_size, void* d_ws, size_t ws_size,
                              hipStream_t stream) {
  const float* x      = (const float*)d_in[0];
  const float* w1     = (const float*)d_in[1];
  const float* w2     = (const float*)d_in[2];
  const float* w3     = (const float*)d_in[3];
  const float* fc1_w  = (const float*)d_in[4];
  const float* fc1_b  = (const float*)d_in[5];
  const float* out_w  = (const float*)d_in[6];
  const float* out_b  = (const float*)d_in[7];
  float* out = (float*)d_out;   // [volts 30*320 | w1 100 | w2 20480]
  float* out_w1 = out + T_STEPS*N_FEAT;
  float* out_w2 = out_w1 + C1*25;

  char* p = (char*)d_ws;
  float* v1 = (float*)p;                  p += (size_t)N_V1*4;
  float* z9 = (float*)p;                  p += (size_t)T_STEPS*N_FEAT*4;
  int* alive_flag = (int*)p;              p += 4;
  p += 60;                                // pad to 64B
  unsigned char* m1 = (unsigned char*)p;  p += N_V1;
  unsigned char* z2 = (unsigned char*)p;  p += N_V1;
  unsigned char* z3 = (unsigned char*)p;  p += N_Z3;

  k1_conv1pool<<<K1_BLOCKS, NTHR, 0, stream>>>(x, w1, w2, z3, alive_flag, z9,
                                               out_w1, out_w2);
  k2_batch<<<BATCH, NTHR, 0, stream>>>(z3, x, w1, w2, w3,
                                       v1, m1, z2, z9, alive_flag);
  f2_head<<<1, NTHR, 0, stream>>>(z9, fc1_w, fc1_b, out_w, out_b,
                                  out, alive_flag);
}

// Round 14
// 40.261 us; speedup vs baseline: 4.1746x; 4.1746x over previous
//
#include <hip/hip_runtime.h>

// ConvNet_STDP — 4 regular kernels, stream-ordered, NO cooperative launch.
//
// Verified (rounds 1-13, absmax 0.0):
//  * STDP provably inert -> weight outputs are clip(w_init, 0, 1).
//  * Network dies at t=0 for this input; gated self-contained fallback
//    (recomputes everything from x, exact reference order) guards any input.
//  * R13 post-mortem: consolidating into 32-block kernels -> latency-bound
//    (occupancy 1.5%, 175us). Bodies dominate, boundaries are ~2-3us.
//  * R14: R12 skeleton + conv3 stage widened: (b,c3)=320 blocks, z5+w3
//    staged in LDS, 25-tap chains, 32-lane shfl reduce. Fallback lives in
//    c3==0 blocks when alive (fast path skips -> no write race).

#define T_STEPS 30
#define BATCH   32
#define H_IN    240
#define W_IN    160
#define C1      4
#define H1      236
#define W1O     156
#define H3      39
#define W3      25
#define C2      20
#define H2      24
#define W2O     10
#define C3      10
#define H8      8

#define N1PB   (C1*H1*W1O)         // 147,264 per-batch conv1 positions
#define N_V1   (BATCH*N1PB)        // 4,712,448
#define N_V2PB (C2*H2*W2O)         // 4,800
#define Z3PB   (C1*H3*W3)          // 3,900
#define N_Z3   (BATCH*Z3PB)        // 124,800
#define N_POOL (BATCH*H3*W3)       // 31,200
#define N_FEAT (BATCH*C3)          // 320

#define NTHR 256
#define K1_BLOCKS 975              // N_POOL*8 / 256 exactly

// 64-lane sum, pure VALU (DPP). Result valid in lane 63 only.
__device__ __forceinline__ float wave64_sum_dpp(float s) {
  s += __int_as_float(__builtin_amdgcn_update_dpp(0, __float_as_int(s), 0x111, 0xf, 0xf, true)); // row_shr:1
  s += __int_as_float(__builtin_amdgcn_update_dpp(0, __float_as_int(s), 0x112, 0xf, 0xf, true)); // row_shr:2
  s += __int_as_float(__builtin_amdgcn_update_dpp(0, __float_as_int(s), 0x114, 0xf, 0xf, true)); // row_shr:4
  s += __int_as_float(__builtin_amdgcn_update_dpp(0, __float_as_int(s), 0x118, 0xf, 0xf, true)); // row_shr:8
  s += __int_as_float(__builtin_amdgcn_update_dpp(0, __float_as_int(s), 0x142, 0xa, 0xf, true)); // row_bcast:15
  s += __int_as_float(__builtin_amdgcn_update_dpp(0, __float_as_int(s), 0x143, 0xc, 0xf, true)); // row_bcast:31
  return s;
}

// ---- K1: fused conv1+pool1 (t=0, stateless) -> z3; init alive_flag;
//      weight-clip outputs ----
__global__ __launch_bounds__(NTHR) void k1_conv1pool(
    const float* __restrict__ x, const float* __restrict__ w1,
    const float* __restrict__ w2,
    unsigned char* __restrict__ z3, int* alive_flag,
    float* __restrict__ out_w1, float* __restrict__ out_w2)
{
  __shared__ float s_w1[C1*25];
  for (int i = threadIdx.x; i < C1*25; i += NTHR) s_w1[i] = w1[i];
  __syncthreads();
  int it = blockIdx.x*NTHR + threadIdx.x;
  const int gsz = K1_BLOCKS*NTHR;
  if (it == 0) *alive_flag = 0;
  for (int i = it; i < C1*25;     i += gsz) out_w1[i] = fminf(fmaxf(w1[i], 0.f), 1.f);
  for (int i = it; i < C2*C1*256; i += gsz) out_w2[i] = fminf(fmaxf(w2[i], 0.f), 1.f);
  int o = it >> 3, q = it & 7;
  int px = o % W3; int tt = o / W3;
  int py = tt % H3; int b = tt / H3;
  unsigned mask = 0;
  if (q < 7) {
    const float* xb = x + (size_t)b*H_IN*W_IN;
    int ybase = py*6 + q;                       // this lane's window row
    float acc[C1][7];
    #pragma unroll
    for (int c = 0; c < C1; ++c)
      #pragma unroll
      for (int wx = 0; wx < 7; ++wx) acc[c][wx] = 0.f;
    #pragma unroll
    for (int i = 0; i < 5; ++i) {
      const float* xp = xb + (size_t)(ybase + i)*W_IN + px*6;
      float xr[11];
      #pragma unroll
      for (int k = 0; k < 11; ++k) xr[k] = xp[k];
      #pragma unroll
      for (int j = 0; j < 5; ++j) {
        float w0 = s_w1[ 0 + i*5 + j];
        float w1v = s_w1[25 + i*5 + j];
        float w2v = s_w1[50 + i*5 + j];
        float w3v = s_w1[75 + i*5 + j];
        #pragma unroll
        for (int wx = 0; wx < 7; ++wx) {
          float xv = xr[wx + j];
          acc[0][wx] = fmaf(xv, w0,  acc[0][wx]);
          acc[1][wx] = fmaf(xv, w1v, acc[1][wx]);
          acc[2][wx] = fmaf(xv, w2v, acc[2][wx]);
          acc[3][wx] = fmaf(xv, w3v, acc[3][wx]);
        }
      }
    }
    #pragma unroll
    for (int c = 0; c < C1; ++c)
      #pragma unroll
      for (int wx = 0; wx < 7; ++wx)
        mask |= (acc[c][wx] >= 10.f) ? (1u << c) : 0u;
  }
  mask |= __shfl_xor(mask, 1, 64);
  mask |= __shfl_xor(mask, 2, 64);
  mask |= __shfl_xor(mask, 4, 64);
  if (q == 0 && o < N_POOL) {
    unsigned char* zp = z3 + (size_t)b*Z3PB + py*W3 + px;
    zp[0]        =  mask       & 1;
    zp[H3*W3]    = (mask >> 1) & 1;
    zp[2*H3*W3]  = (mask >> 2) & 1;
    zp[3*H3*W3]  = (mask >> 3) & 1;
  }
}

// ---- K2: conv2 + IAF(60) (t=0) -> z5; alive_flag. One wave = one output
//      row; no LDS, no sync; mask packed from global per lane. ----
__global__ __launch_bounds__(NTHR) void k2_conv2(
    const unsigned char* __restrict__ z3, const float* __restrict__ w2,
    unsigned char* __restrict__ z5, int* alive_flag)
{
  // grid = 3840 = 32 b x 20 c x 6 oy-groups; wave wv handles oy = g*4+wv
  const int b  = blockIdx.x & 31;
  const int cg = blockIdx.x >> 5;               // 0..119
  const int c  = cg / 6;
  const int g  = cg - c*6;
  const int tid = threadIdx.x;
  const int lane = tid & 63;
  const int wv = tid >> 6;
  const int oy = g*4 + wv;                      // 0..23
  const int ci = lane >> 4, ii = lane & 15;
  float wreg[16];                               // w2[c][ci][ii][0..16)
  {
    const float4* wp = (const float4*)(w2 + ((size_t)c*C1 + ci)*256 + ii*16);
    #pragma unroll
    for (int k = 0; k < 4; ++k) {
      float4 v = wp[k];
      wreg[4*k+0] = v.x; wreg[4*k+1] = v.y; wreg[4*k+2] = v.z; wreg[4*k+3] = v.w;
    }
  }
  unsigned mw = 0;                              // packed 25-bit window row
  {
    const unsigned char* rp = z3 + (size_t)b*Z3PB + (ci*H3 + oy + ii)*W3;
    #pragma unroll
    for (int k = 0; k < W3; ++k) mw |= (rp[k] ? 1u : 0u) << k;
  }
  int surv = 0;
  #pragma unroll
  for (int ox = 0; ox < 10; ++ox) {
    unsigned mm = mw >> ox;
    float s = 0.f;
    #pragma unroll
    for (int j = 0; j < 16; ++j)
      s += (mm & (1u << j)) ? wreg[j] : 0.f;    // register taps
    s = wave64_sum_dpp(s);                      // pure-VALU reduce -> lane 63
    if (lane == 63) {
      unsigned char sp = (s >= 60.0f) ? 1 : 0;
      z5[b*N_V2PB + c*(H2*W2O) + oy*W2O + ox] = sp;
      surv |= (sp == 0);
    }
  }
  if (lane == 63 && surv) *alive_flag = 1;      // plain store; dead: no store
}

// ---- K3W: grid (b,c3)=320 blocks. Dead (measured): stage z5[b]+w3[c3] in
//      LDS, conv3 (pool folded) with 25-tap lane chains -> z9[0][b][c3].
//      Alive: c3==0 blocks run the exact self-contained fallback. ----
__global__ __launch_bounds__(NTHR) void k3_wide(
    const unsigned char* __restrict__ z5g, const float* __restrict__ w3,
    const float* __restrict__ x,  const float* __restrict__ w1,
    const float* __restrict__ w2,
    float* v1, unsigned char* m1, unsigned char* z2,
    float* __restrict__ z9, const int* alive_flag)
{
  const int b  = blockIdx.x & 31;
  const int c3 = blockIdx.x >> 5;               // 0..9
  const int tid = threadIdx.x;
  const bool alive = (*alive_flag != 0);        // k2 finished (stream order)

  if (!alive) {
    // ---- fast conv3 for (b, c3): LDS-staged, 25-tap chains ----
    __shared__ unsigned int s_z5w[N_V2PB/4];    // 4800 B
    __shared__ float s_w3c[C2*25];              // 2000 B
    __shared__ unsigned char s_sp[8];
    {
      const unsigned int* src = (const unsigned int*)(z5g + (size_t)b*N_V2PB);
      for (int i = tid; i < N_V2PB/4; i += NTHR) s_z5w[i] = src[i];
      const float* wsrc = w3 + (size_t)c3*C2*25;
      if (tid < C2*25) s_w3c[tid] = wsrc[tid];
    }
    __syncthreads();
    const unsigned char* sz = (const unsigned char*)s_z5w;
    int oy = tid >> 5, l = tid & 31;            // 8 outputs x 32 lanes
    float s = 0.f;
    if (l < C2) {                               // lane = one input channel
      const unsigned char* zp = sz + l*H2*W2O;
      const float* wp = s_w3c + l*25;
      #pragma unroll
      for (int i = 0; i < 5; ++i) {
        const unsigned char* r0 = zp + (2*(oy + i))*W2O;
        const unsigned char* r1 = r0 + W2O;
        #pragma unroll
        for (int j = 0; j < 5; ++j) {
          unsigned char zv = r0[2*j] | r0[2*j+1] | r1[2*j] | r1[2*j+1];
          s = fmaf((float)zv, wp[i*5 + j], s);
        }
      }
    }
    s += __shfl_xor(s, 1, 64);                  // offsets <32: stays in half
    s += __shfl_xor(s, 2, 64);
    s += __shfl_xor(s, 4, 64);
    s += __shfl_xor(s, 8, 64);
    s += __shfl_xor(s, 16, 64);
    if (l == 0) s_sp[oy] = (s >= 2.0f) ? 1 : 0; // IAF t=0: v=s, m=1
    __syncthreads();
    if (tid == 0) {
      unsigned char r = 0;
      #pragma unroll
      for (int k = 0; k < H8; ++k) r |= s_sp[k];
      z9[b*C3 + c3] = (float)r;                 // z9[0][b][c3]
    }
    return;
  }

  // ---- alive: only c3==0 blocks run the exact per-batch fallback ----
  if (c3 != 0) return;
  __shared__ float s_w1[C1*25];
  __shared__ unsigned char s_z3[Z3PB];
  __shared__ float s_v2[N_V2PB];
  __shared__ unsigned char s_m2[N_V2PB], s_z5[N_V2PB];
  __shared__ float s_v3[C3*H8];
  __shared__ unsigned char s_m3[C3*H8], s_z8[C3*H8];

  for (int i = tid; i < C1*25; i += NTHR) s_w1[i] = w1[i];
  float* v1b = v1 + (size_t)b*N1PB;
  unsigned char* m1b = m1 + (size_t)b*N1PB;
  unsigned char* z2b = z2 + (size_t)b*N1PB;
  __syncthreads();

  // t=0: conv1 state (exact order). Fired at t=0 <=> m1b==0.
  const float* x0 = x + (size_t)b*H_IN*W_IN;
  for (int idx = tid; idx < N1PB; idx += NTHR) {
    int xw = idx % W1O; int r = idx / W1O;
    int y  = r % H1;    int c = r / H1;
    const float* xp = x0 + (size_t)y*W_IN + xw;
    const float* wp = s_w1 + c*25;
    float s = 0.f;
    #pragma unroll
    for (int i = 0; i < 5; ++i)
      #pragma unroll
      for (int j = 0; j < 5; ++j) s = fmaf(xp[i*W_IN + j], wp[i*5 + j], s);
    bool z = (s >= 10.0f);
    v1b[idx] = z ? 0.f : s;
    m1b[idx] = z ? 0 : 1;
  }
  __syncthreads();
  // t=0: pool1 from m1b (spike <=> mask cleared at t=0)
  for (int i = tid; i < Z3PB; i += NTHR) {
    int px = i % W3; int r = i / W3;
    int py = r % H3; int cc = r / H3;
    const unsigned char* p = m1b + ((size_t)cc*H1 + py*6)*W1O + px*6;
    unsigned char rr = 0;
    #pragma unroll
    for (int ii = 0; ii < 7; ++ii)
      #pragma unroll
      for (int jj = 0; jj < 7; ++jj) rr |= (p[ii*W1O + jj] == 0) ? 1 : 0;
    s_z3[i] = rr;
  }
  __syncthreads();
  // t=0: conv2 state + exact z5
  for (int o = tid; o < N_V2PB; o += NTHR) {
    int c  = o / (H2*W2O);
    int r  = o - c*(H2*W2O);
    int oy = r / W2O, ox = r - (r/W2O)*W2O;
    const float* wb = w2 + (size_t)c*C1*256;
    float s = 0.f;
    for (int ci = 0; ci < C1; ++ci)
      for (int i = 0; i < 16; ++i) {
        const unsigned char* ip = s_z3 + (ci*H3 + oy + i)*W3 + ox;
        const float* wp = wb + ci*256 + i*16;
        #pragma unroll
        for (int j = 0; j < 16; ++j) s = fmaf((float)ip[j], wp[j], s);
      }
    bool z = (s >= 60.0f);
    s_v2[o] = z ? 0.f : s;
    s_m2[o] = z ? 0 : 1;
    s_z5[o] = z ? 1 : 0;                        // t=0: m=1 -> spike = z
  }
  __syncthreads();
  // t=0: conv3 state + z8 (from exact z5)
  for (int o = tid; o < C3*H8; o += NTHR) {
    int cc3 = o >> 3, oy = o & 7;
    float s = 0.f;
    for (int ci = 0; ci < C2; ++ci) {
      const unsigned char* zp = s_z5 + ci*H2*W2O;
      const float* wp = w3 + ((size_t)cc3*C2 + ci)*25;
      #pragma unroll
      for (int i = 0; i < 5; ++i) {
        const unsigned char* r0 = zp + (2*(oy + i))*W2O;
        const unsigned char* r1 = r0 + W2O;
        #pragma unroll
        for (int j = 0; j < 5; ++j) {
          unsigned char zv = r0[2*j] | r0[2*j+1] | r1[2*j] | r1[2*j+1];
          s = fmaf((float)zv, wp[i*5 + j], s);
        }
      }
    }
    bool z = (s >= 2.0f);
    s_v3[o] = z ? 0.f : s;
    s_m3[o] = z ? 0 : 1;
    s_z8[o] = z ? 1 : 0;                        // t=0: m=1
  }
  __syncthreads();
  if (tid < C3) {                               // exact z9[0][b]
    unsigned char r = 0;
    #pragma unroll
    for (int k = 0; k < H8; ++k) r |= s_z8[tid*H8 + k];
    z9[b*C3 + tid] = (float)r;
  }
  __syncthreads();

  // exact recurrence t = 1..29 for this batch
  for (int t = 1; t < T_STEPS; ++t) {
    const float* xt = x + ((size_t)t*BATCH + b)*H_IN*W_IN;
    for (int idx = tid; idx < N1PB; idx += NTHR) {        // conv1+IAF
      int xw = idx % W1O; int r = idx / W1O;
      int y  = r % H1;    int c = r / H1;
      const float* xp = xt + (size_t)y*W_IN + xw;
      const float* wp = s_w1 + c*25;
      float s = 0.f;
      #pragma unroll
      for (int i = 0; i < 5; ++i)
        #pragma unroll
        for (int j = 0; j < 5; ++j) s = fmaf(xp[i*W_IN + j], wp[i*5 + j], s);
      float v = v1b[idx] + s;
      bool  z = (v >= 10.0f);
      v1b[idx] = z ? 0.f : v;
      unsigned char m = m1b[idx];
      z2b[idx] = (z && m) ? 1 : 0;
      m1b[idx] = (m && !z) ? 1 : 0;
    }
    __syncthreads();
    for (int i = tid; i < Z3PB; i += NTHR) {              // pool1 = OR
      int px = i % W3; int r = i / W3;
      int py = r % H3; int c = r / H3;
      const unsigned char* p = z2b + ((size_t)c*H1 + py*6)*W1O + px*6;
      unsigned char rr = 0;
      #pragma unroll
      for (int ii = 0; ii < 7; ++ii)
        #pragma unroll
        for (int jj = 0; jj < 7; ++jj) rr |= p[ii*W1O + jj];
      s_z3[i] = rr;
    }
    __syncthreads();
    for (int o = tid; o < N_V2PB; o += NTHR) {            // conv2+IAF
      int c  = o / (H2*W2O);
      int r  = o - c*(H2*W2O);
      int oy = r / W2O, ox = r - (r/W2O)*W2O;
      const float* wb = w2 + (size_t)c*C1*256;
      float s = 0.f;
      for (int ci = 0; ci < C1; ++ci)
        for (int i = 0; i < 16; ++i) {
          const unsigned char* ip = s_z3 + (ci*H3 + oy + i)*W3 + ox;
          const float* wp = wb + ci*256 + i*16;
          #pragma unroll
          for (int j = 0; j < 16; ++j) s = fmaf((float)ip[j], wp[j], s);
        }
      float v = s_v2[o] + s;
      bool  z = (v >= 60.0f);
      s_v2[o] = z ? 0.f : v;
      unsigned char m = s_m2[o];
      s_z5[o] = (z && m) ? 1 : 0;
      s_m2[o] = (m && !z) ? 1 : 0;
    }
    __syncthreads();
    for (int o = tid; o < C3*H8; o += NTHR) {             // conv3+IAF (pool folded)
      int cc3 = o >> 3, oy = o & 7;
      float s = 0.f;
      for (int ci = 0; ci < C2; ++ci) {
        const unsigned char* zp = s_z5 + ci*H2*W2O;
        const float* wp = w3 + ((size_t)cc3*C2 + ci)*25;
        #pragma unroll
        for (int i = 0; i < 5; ++i) {
          const unsigned char* r0 = zp + (2*(oy + i))*W2O;
          const unsigned char* r1 = r0 + W2O;
          #pragma unroll
          for (int j = 0; j < 5; ++j) {
            unsigned char zv = r0[2*j] | r0[2*j+1] | r1[2*j] | r1[2*j+1];
            s = fmaf((float)zv, wp[i*5 + j], s);
          }
        }
      }
      float v = s_v3[o] + s;
      bool  z = (v >= 2.0f);
      s_v3[o] = z ? 0.f : v;
      unsigned char m = s_m3[o];
      s_z8[o] = (z && m) ? 1 : 0;
      s_m3[o] = (m && !z) ? 1 : 0;
    }
    __syncthreads();
    if (tid < C3) {                                       // z9[t][b][c]
      unsigned char r = 0;
      #pragma unroll
      for (int k = 0; k < H8; ++k) r |= s_z8[tid*H8 + k];
      z9[(size_t)t*N_FEAT + b*C3 + tid] = (float)r;
    }
    __syncthreads();
  }
}

// ---- F2: readout head, single block (closed-form tail when all dead) ----
__global__ __launch_bounds__(NTHR) void f2_head(
    const float* __restrict__ z9,
    const float* __restrict__ fc1_w, const float* __restrict__ fc1_b,
    const float* __restrict__ out_w, const float* __restrict__ out_b,
    float* __restrict__ out, const int* alive_flag)
{
  const int tid = threadIdx.x;
  __shared__ float s_feat[N_FEAT], s_h[64], s_li[10], s_lv[10];
  __shared__ float s_tail[T_STEPS*10];
  if (tid < 10) { s_li[tid] = 0.f; s_lv[tid] = 0.f; }
  __syncthreads();
  const bool alive = (*alive_flag != 0);
  const int tmax = alive ? T_STEPS : 1;

  for (int t = 0; t < tmax; ++t) {
    for (int i = tid; i < N_FEAT; i += NTHR) s_feat[i] = z9[(size_t)t*N_FEAT + i];
    __syncthreads();
    {
      int o = tid >> 2, q = tid & 3;            // 4 lanes per fc1 output
      if (o < 50) {
        const float* wr = fc1_w + (size_t)o*N_FEAT + q*80;
        const float* fr = s_feat + q*80;
        float s = 0.f;
        for (int j = 0; j < 80; ++j) s = fmaf(fr[j], wr[j], s);
        s += __shfl_xor(s, 1, 64);
        s += __shfl_xor(s, 2, 64);
        if (q == 0) s_h[o] = fmaxf(s + fc1_b[o], 0.f);
      }
    }
    __syncthreads();
    if (tid < 10) {
      float idec = s_li[tid]*0.8f;              // 1 - dt*tau_syn_inv
      float vnew = s_lv[tid] + 0.1f*(idec - s_lv[tid]);
      float acc = idec + out_b[tid];
      for (int k = 0; k < 50; ++k) acc = fmaf(s_h[k], out_w[tid*50 + k], acc);
      s_li[tid] = acc;
      s_lv[tid] = vnew;
    }
    __syncthreads();
    float* vt = out + (size_t)t*N_FEAT;
    for (int i = tid; i < N_FEAT; i += NTHR) vt[i] = s_lv[i % 10];
    __syncthreads();
  }

  if (!alive) {                                 // closed-form tail t=1..29
    if (tid < 50) s_h[tid] = fmaxf(fc1_b[tid], 0.f);
    __syncthreads();
    if (tid < 10) {
      float c = out_b[tid];
      for (int k = 0; k < 50; ++k) c = fmaf(s_h[k], out_w[tid*50 + k], c);
      float li = s_li[tid], lv = s_lv[tid];
      for (int tt = 1; tt < T_STEPS; ++tt) {
        float idec = li*0.8f;
        lv = lv + 0.1f*(idec - lv);
        li = idec + c;
        s_tail[(tt - 1)*10 + tid] = lv;
      }
    }
    __syncthreads();
    int nrem = (T_STEPS - 1)*N_FEAT;
    float* vt = out + (size_t)N_FEAT;
    for (int i = tid; i < nrem; i += NTHR)
      vt[i] = s_tail[(i/N_FEAT)*10 + (i % 10)];
  }
}

extern "C" void kernel_launch(void* const* d_in, const int* in_sizes, int n_in,
                              void* d_out, int out_size, void* d_ws, size_t ws_size,
                              hipStream_t stream) {
  const float* x      = (const float*)d_in[0];
  const float* w1     = (const float*)d_in[1];
  const float* w2     = (const float*)d_in[2];
  const float* w3     = (const float*)d_in[3];
  const float* fc1_w  = (const float*)d_in[4];
  const float* fc1_b  = (const float*)d_in[5];
  const float* out_w  = (const float*)d_in[6];
  const float* out_b  = (const float*)d_in[7];
  float* out = (float*)d_out;   // [volts 30*320 | w1 100 | w2 20480]
  float* out_w1 = out + T_STEPS*N_FEAT;
  float* out_w2 = out_w1 + C1*25;

  char* p = (char*)d_ws;
  float* v1 = (float*)p;                  p += (size_t)N_V1*4;
  float* z9 = (float*)p;                  p += (size_t)T_STEPS*N_FEAT*4;
  int* alive_flag = (int*)p;              p += 4;
  p += 60;                                // pad to 64B
  unsigned char* m1 = (unsigned char*)p;  p += N_V1;
  unsigned char* z2 = (unsigned char*)p;  p += N_V1;
  unsigned char* z3 = (unsigned char*)p;  p += N_Z3;
  unsigned char* z5 = (unsigned char*)p;  p += BATCH*N_V2PB;

  k1_conv1pool<<<K1_BLOCKS, NTHR, 0, stream>>>(x, w1, w2, z3, alive_flag,
                                               out_w1, out_w2);
  k2_conv2<<<BATCH*C2*6, NTHR, 0, stream>>>(z3, w2, z5, alive_flag); // 3840
  k3_wide<<<BATCH*C3, NTHR, 0, stream>>>(z5, w3, x, w1, w2,
                                         v1, m1, z2, z9, alive_flag); // 320
  f2_head<<<1, NTHR, 0, stream>>>(z9, fc1_w, fc1_b, out_w, out_b,
                                  out, alive_flag);
}